// Round 3
// baseline (284.388 us; speedup 1.0000x reference)
//
#include <hip/hip_runtime.h>
#include <hip/hip_cooperative_groups.h>
#include <hip/hip_fp16.h>
#include <hip/hip_fp8.h>

namespace cg = cooperative_groups;

#define M 9
#define NWIN 2
typedef _Float16 h16;
#define SENT 0x7FFFFFF0

// ---- bucketed-sweep path constants ----
#define GRAN 4096   // bucket granularity in points (n >> 12)
#define WS2 8192    // phase-2 window points (2 buckets, 32KB)
#define WS3 4096    // phase-3 window points (1 bucket, 16KB per array)
#define BPTS 4096   // points per block
#define BLK 1024    // threads per block
#define PPT 4       // points per thread

// LDS layout (dword offsets). Total 37396 dwords = 149,584 B (< 160 KiB).
#define OFF_WIN 0       // 16384 dw: window double-buffers
#define OFF_B 16384     // 16384 dw: phase2 acc4 (64KB) / phase3 acc1+invqt+Kt
#define OFF_PW1 32768   // 4096 dw: per-point packed1 table
#define OFF_BST 36864   // 260 int: bucket starts (prefix)
#define OFF_CUR 37124   // 256 int: scatter cursors
#define OFF_RED 37380   // 16 float: reduction buffer
#define SMEM_DW 37396

__device__ __forceinline__ uint32_t pack_e4m3x4(float a, float b, float c, float d) {
  __hip_fp8_e4m3 pa(a), pb(b), pc(c), pd(d);
  return (uint32_t)pa.__x | ((uint32_t)pb.__x << 8) |
         ((uint32_t)pc.__x << 16) | ((uint32_t)pd.__x << 24);
}
__device__ __forceinline__ float e4m3_byte(uint32_t w, int byte) {
  __hip_fp8_e4m3 t;
  t.__x = (__hip_fp8_storage_t)((w >> (8 * byte)) & 0xffu);
  return (float)t;
}

__device__ __forceinline__ void block_reduce_atomic(float part, float* out,
                                                    int tid) {
#pragma unroll
  for (int off = 32; off > 0; off >>= 1) part += __shfl_down(part, off, 64);
  __shared__ float sbuf[4];
  int lane = tid & 63;
  int wave = tid >> 6;
  if (lane == 0) sbuf[wave] = part;
  __syncthreads();
  if (tid == 0) atomicAdd(out, sbuf[0] + sbuf[1] + sbuf[2] + sbuf[3]);
}

// ======================= bucketed-sweep cooperative kernel ==================
// All random access is in LDS; global reads are streaming only.
__global__ __launch_bounds__(BLK) void fused_bucket(
    const float2* __restrict__ x,
    const float* __restrict__ ut,
    const float* __restrict__ ut1,
    const float* __restrict__ up,
    const float* __restrict__ usol,
    const float4* __restrict__ inv,
    const int* __restrict__ nidx,
    uint32_t* __restrict__ p1,     // padded packed1
    uint32_t* __restrict__ p2,     // padded packed2
    uint32_t* __restrict__ items,  // nblk * 36864 items (n:20 | pid:12)
    float* __restrict__ out,
    int N) {
  cg::grid_group grid = cg::this_grid();
  __shared__ __align__(16) uint32_t smem[SMEM_DW];
  uint32_t* winA = smem + OFF_WIN;
  uint32_t* regB = smem + OFF_B;
  uint32_t* pw1t = smem + OFF_PW1;
  int* bst = (int*)(smem + OFF_BST);
  int* cur = (int*)(smem + OFF_CUR);
  float* sred = (float*)(smem + OFF_RED);

  const int b = blockIdx.x;
  const int lt = (int)threadIdx.x;
  const int pbase = b * BPTS;
  const int nb = (N + GRAN - 1) / GRAN;
  uint32_t* mit = items + (size_t)b * (BPTS * M);

  float part = 0.f;
  uint32_t invq[PPT];
  h16 f0r[PPT];
  uint32_t myn[PPT][M];

  for (int k = lt; k <= nb; k += BLK) bst[k] = 0;

  // ---- Phase 1: pack granule, self tables, loss_u, read nidx --------------
#pragma unroll
  for (int p = 0; p < PPT; ++p) {
    int pid = p * BLK + lt;
    int i = pbase + pid;
    if (i < N) {
      float2 xi = x[i];
      uint32_t bx = (uint32_t)__float2int_rn(xi.x * 255.f);
      uint32_t by = (uint32_t)__float2int_rn(xi.y * 255.f);
      float u = __builtin_nontemporal_load(&ut[i]);
      float u1 = __builtin_nontemporal_load(&ut1[i]);
      __hip_fp8_e4m3 eu(u), eu1(u1);
      uint32_t w = bx | (by << 8) | ((uint32_t)eu.__x << 16) |
                   ((uint32_t)eu1.__x << 24);
      p1[i] = w;
      pw1t[pid] = w;
      float f0v = u1 - u - 0.01f * (u - u * u * u + u1 - u1 * u1 * u1);
      f0r[p] = (h16)f0v;
      float4 iv = inv[i];
      invq[p] = pack_e4m3x4(iv.x, iv.y, iv.z, iv.w);
      float du = __builtin_nontemporal_load(&up[i]) -
                 __builtin_nontemporal_load(&usol[i]);
      part += du * du;
#pragma unroll
      for (int m = 0; m < M; ++m)
        myn[p][m] = (uint32_t)__builtin_nontemporal_load(&nidx[(size_t)i * M + m]);
    } else {
      invq[p] = 0u;
      f0r[p] = (h16)0.f;
      pw1t[pid] = 0u;
#pragma unroll
      for (int m = 0; m < M; ++m) myn[p][m] = 0xFFFFFFFFu;
    }
  }
  __syncthreads();
  // histogram by bucket (n >> 12)
#pragma unroll
  for (int p = 0; p < PPT; ++p)
#pragma unroll
    for (int m = 0; m < M; ++m)
      if (myn[p][m] != 0xFFFFFFFFu)
        atomicAdd(&bst[1 + (int)(myn[p][m] >> 12)], 1);
  __syncthreads();
  if (lt == 0)
    for (int k = 1; k <= nb; ++k) bst[k] += bst[k - 1];
  __syncthreads();
  for (int k = lt; k < nb; k += BLK) cur[k] = bst[k];
  __syncthreads();
  // scatter items (fire-and-forget 4B stores into this block's region)
#pragma unroll
  for (int p = 0; p < PPT; ++p) {
    int pid = p * BLK + lt;
#pragma unroll
    for (int m = 0; m < M; ++m) {
      uint32_t n = myn[p][m];
      if (n != 0xFFFFFFFFu) {
        int off = atomicAdd(&cur[(int)(n >> 12)], 1);
        mit[off] = n | ((uint32_t)pid << 20);
      }
    }
  }
  __threadfence();
  grid.sync();
  __threadfence();

  // ---- Phase 2: windowed sweep of packed1; LDS accumulate s0,s1,t0,t1 -----
  float* acc4 = (float*)regB;
  {
    const uint4* g4 = (const uint4*)p1;
    uint4 a0 = g4[lt], a1 = g4[1024 + lt];  // preload window 0
    for (int k = lt; k < BPTS * 4; k += BLK) acc4[k] = 0.f;
    int nw2 = (nb + 1) >> 1;
    int ehi0 = (2 <= nb) ? 2 : nb;
    int s = bst[0], e = bst[ehi0];
    int have = (s + lt < e);
    uint32_t itp = have ? mit[s + lt] : 0u;
    __syncthreads();
    for (int w = 0; w < nw2; ++w) {
      uint32_t* wb = winA + (w & 1) * WS2;
      ((uint4*)wb)[lt] = a0;
      ((uint4*)wb)[1024 + lt] = a1;
      int s1 = 0, e1 = 0;
      if (w + 1 < nw2) {
        a0 = g4[(w + 1) * 2048 + lt];
        a1 = g4[(w + 1) * 2048 + 1024 + lt];
        int hi = 2 * w + 4;
        if (hi > nb) hi = nb;
        s1 = bst[2 * w + 2];
        e1 = bst[hi];
      }
      int have1 = (w + 1 < nw2) && (s1 + lt < e1);
      uint32_t itn = have1 ? mit[s1 + lt] : 0u;
      __syncthreads();
      int lo = w * WS2;
#define PROC2(IT)                                                         \
      do {                                                                \
        uint32_t n_ = (IT) & 0xFFFFFu;                                    \
        int pid_ = (int)((IT) >> 20);                                     \
        uint32_t qw_ = wb[n_ - (uint32_t)lo];                             \
        uint32_t pw_ = pw1t[pid_];                                        \
        float dx_ = ((float)(qw_ & 255u) - (float)(pw_ & 255u)) * (1.f / 255.f); \
        float dy_ = ((float)((qw_ >> 8) & 255u) - (float)((pw_ >> 8) & 255u)) * (1.f / 255.f); \
        float du_ = e4m3_byte(qw_, 2) - e4m3_byte(pw_, 2);                \
        float du1_ = e4m3_byte(qw_, 3) - e4m3_byte(pw_, 3);               \
        atomicAdd(acc4 + pid_ * 4 + 0, du_ * dx_);                        \
        atomicAdd(acc4 + pid_ * 4 + 1, du_ * dy_);                        \
        atomicAdd(acc4 + pid_ * 4 + 2, du1_ * dx_);                       \
        atomicAdd(acc4 + pid_ * 4 + 3, du1_ * dy_);                       \
      } while (0)
      if (have) PROC2(itp);
      for (int k = s + BLK + lt; k < e; k += BLK) {
        uint32_t it = mit[k];
        PROC2(it);
      }
#undef PROC2
      itp = itn;
      have = have1;
      s = s1;
      e = e1;
    }
  }
  __syncthreads();
  // epilogue: snapshot accs, then rebuild region B as acc1 + tables
  float sv[PPT][4];
#pragma unroll
  for (int p = 0; p < PPT; ++p) {
    int pid = p * BLK + lt;
#pragma unroll
    for (int c = 0; c < 4; ++c) sv[p][c] = acc4[pid * 4 + c];
  }
  __syncthreads();
  float* acc1 = (float*)regB;
  uint32_t* invqt = regB + BPTS;
  float2* Kt = (float2*)(regB + 2 * BPTS);
#pragma unroll
  for (int p = 0; p < PPT; ++p) {
    int pid = p * BLK + lt;
    int i = pbase + pid;
    uint32_t iq = invq[p];
    float a_ = e4m3_byte(iq, 0), b_ = e4m3_byte(iq, 1);
    float c_ = e4m3_byte(iq, 2), d_ = e4m3_byte(iq, 3);
    uint32_t w2 = 0u;
    if (i < N) {
      w2 = pack_e4m3x4(sv[p][0] * a_ + sv[p][1] * c_,
                       sv[p][0] * b_ + sv[p][1] * d_,
                       sv[p][2] * a_ + sv[p][3] * c_,
                       sv[p][2] * b_ + sv[p][3] * d_);
      p2[i] = w2;
    }
    float si = e4m3_byte(w2, 0) + e4m3_byte(w2, 2);
    float ti = e4m3_byte(w2, 1) + e4m3_byte(w2, 3);
    Kt[pid] = make_float2(si * a_ + ti * b_, si * c_ + ti * d_);
    invqt[pid] = iq;
    acc1[pid] = 0.f;
  }
  __threadfence();
  grid.sync();
  __threadfence();

  // ---- Phase 3: windowed sweep of packed1+packed2; single LDS acc ---------
  {
    const uint4* h1 = (const uint4*)p1;
    const uint4* h2 = (const uint4*)p2;
    uint4 c1 = h1[lt], c2 = h2[lt];
    int s = bst[0], e = bst[1];
    int have = (s + lt < e);
    uint32_t itp = have ? mit[s + lt] : 0u;
    for (int w = 0; w < nb; ++w) {
      uint32_t* base_ = winA + (w & 1) * (2 * WS3);
      ((uint4*)base_)[lt] = c1;
      ((uint4*)(base_ + WS3))[lt] = c2;
      int s1 = 0, e1 = 0;
      if (w + 1 < nb) {
        c1 = h1[(w + 1) * 1024 + lt];
        c2 = h2[(w + 1) * 1024 + lt];
        s1 = bst[w + 1];
        e1 = bst[w + 2];
      }
      int have1 = (w + 1 < nb) && (s1 + lt < e1);
      uint32_t itn = have1 ? mit[s1 + lt] : 0u;
      __syncthreads();
      int lo = w * WS3;
#define PROC3(IT)                                                         \
      do {                                                                \
        uint32_t n_ = (IT) & 0xFFFFFu;                                    \
        int pid_ = (int)((IT) >> 20);                                     \
        uint32_t ai_ = n_ - (uint32_t)lo;                                 \
        uint32_t q1_ = base_[ai_];                                        \
        uint32_t q2_ = base_[WS3 + ai_];                                  \
        uint32_t pw_ = pw1t[pid_];                                        \
        uint32_t iq_ = invqt[pid_];                                       \
        float2 K_ = Kt[pid_];                                             \
        float dx_ = ((float)(q1_ & 255u) - (float)(pw_ & 255u)) * (1.f / 255.f); \
        float dy_ = ((float)((q1_ >> 8) & 255u) - (float)((pw_ >> 8) & 255u)) * (1.f / 255.f); \
        float ia_ = e4m3_byte(iq_, 0), ib_ = e4m3_byte(iq_, 1);           \
        float ic_ = e4m3_byte(iq_, 2), id_ = e4m3_byte(iq_, 3);           \
        float sx_ = e4m3_byte(q2_, 0) + e4m3_byte(q2_, 2);                \
        float sy_ = e4m3_byte(q2_, 1) + e4m3_byte(q2_, 3);                \
        float e1_ = dx_ * ia_ + dy_ * ic_;                                \
        float e2_ = dx_ * ib_ + dy_ * id_;                                \
        atomicAdd(acc1 + pid_, sx_ * e1_ + sy_ * e2_ - dx_ * K_.x - dy_ * K_.y); \
      } while (0)
      if (have) PROC3(itp);
      for (int k = s + BLK + lt; k < e; k += BLK) {
        uint32_t it = mit[k];
        PROC3(it);
      }
#undef PROC3
      itp = itn;
      have = have1;
      s = s1;
      e = e1;
    }
  }
  __syncthreads();
#pragma unroll
  for (int p = 0; p < PPT; ++p) {
    int pid = p * BLK + lt;
    int i = pbase + pid;
    if (i < N) {
      float f = (float)f0r[p] - 1e-4f * acc1[pid];
      part += 4.f * f * f;
    }
  }
  // block reduce (16 waves)
#pragma unroll
  for (int off = 32; off > 0; off >>= 1) part += __shfl_down(part, off, 64);
  if ((lt & 63) == 0) sred[lt >> 6] = part;
  __syncthreads();
  if (lt == 0) {
    float tot = 0.f;
    for (int k = 0; k < 16; ++k) tot += sred[k];
    atomicAdd(out, tot);
  }
}

// ======================= previous fused kernel (fallback) ===================
template <int P, int WPE>
__global__ __launch_bounds__(256, WPE) void fused_t(
    const float2* __restrict__ x,
    const float* __restrict__ ut,
    const float* __restrict__ ut1,
    const float* __restrict__ up,
    const float* __restrict__ usol,
    const float4* __restrict__ inv,
    const int* __restrict__ nidx,
    uint32_t* __restrict__ packed1,
    uint32_t* __restrict__ packed2,
    float* __restrict__ out,
    int N) {
  cg::grid_group grid = cg::this_grid();
  const int T = (int)(gridDim.x * blockDim.x);
  const int tid = (int)(blockIdx.x * blockDim.x + threadIdx.x);
  const int lt = (int)threadIdx.x;
  const int l = lt & 63;
  const int wvb = lt & 192;

  __shared__ uint32_t ndv_lds[P * M * 256];

  float part = 0.f;
  uint32_t invq[P];
  uint32_t pw1[P];
  uint32_t pw2[P];
  h16 f0r[P];

#pragma unroll
  for (int p = 0; p < P; ++p) {
    int i = tid + p * T;
    if (i < N) {
      float2 xi = x[i];
      uint32_t bx = (uint32_t)__float2int_rn(xi.x * 255.f);
      uint32_t by = (uint32_t)__float2int_rn(xi.y * 255.f);
      float u = __builtin_nontemporal_load(&ut[i]);
      float u1 = __builtin_nontemporal_load(&ut1[i]);
      __hip_fp8_e4m3 eu(u), eu1(u1);
      uint32_t w = bx | (by << 8) | ((uint32_t)eu.__x << 16) |
                   ((uint32_t)eu1.__x << 24);
      pw1[p] = w;
      packed1[i] = w;
      float f0v = u1 - u - 0.01f * (u - u * u * u + u1 - u1 * u1 * u1);
      f0r[p] = (h16)f0v;
      float4 iv = inv[i];
      invq[p] = pack_e4m3x4(iv.x, iv.y, iv.z, iv.w);
      float du = __builtin_nontemporal_load(&up[i]) -
                 __builtin_nontemporal_load(&usol[i]);
      part += du * du;
    } else {
      pw1[p] = 0u;
      invq[p] = 0u;
      f0r[p] = (h16)0.f;
    }
  }
  __threadfence();
  grid.sync();
  __threadfence();

  const int q = (N + NWIN - 1) / NWIN;
#pragma unroll
  for (int p = 0; p < P; ++p) {
    int i = tid + p * T;
    {
      int i0 = (tid - l) + p * T;
      int gbase = i0 * M;
      uint32_t* stg = &ndv_lds[p * (M * 256)];
#pragma unroll
      for (int m = 0; m < M; ++m) {
        int g = gbase + m * 64 + l;
        uint32_t v = 0u;
        if (g < N * M) v = (uint32_t)__builtin_nontemporal_load(&nidx[g]);
        stg[m * 256 + lt] = v;
      }
    }
    asm volatile("" ::: "memory");
    pw2[p] = 0u;
    if (i < N) {
      uint32_t pw = pw1[p];
      float xi = (float)(pw & 0xffu) * (1.f / 255.f);
      float yi = (float)((pw >> 8) & 0xffu) * (1.f / 255.f);
      float ui = e4m3_byte(pw, 2);
      float u1i = e4m3_byte(pw, 3);
      uint32_t nv[M];
#pragma unroll
      for (int mm = 0; mm < M; ++mm) {
        int r = l * M + mm;
        nv[mm] = ndv_lds[p * (M * 256) + (r >> 6) * 256 + wvb + (r & 63)];
      }
      float s0 = 0.f, s1 = 0.f, t0 = 0.f, t1 = 0.f;
      for (int w = 0; w < NWIN; ++w) {
        int lo = w * q;
#pragma unroll
        for (int m = 0; m < M; ++m) {
          int n = (int)(nv[m] & 0xFFFFFu);
          if ((unsigned)(n - lo) < (unsigned)q) {
            uint32_t qw = packed1[n];
            float dx = (float)(qw & 0xffu) * (1.f / 255.f) - xi;
            float dy = (float)((qw >> 8) & 0xffu) * (1.f / 255.f) - yi;
            float du = e4m3_byte(qw, 2) - ui;
            float du1 = e4m3_byte(qw, 3) - u1i;
            uint32_t qx = (uint32_t)__float2int_rn((dx + 1.f) * 31.5f);
            uint32_t qy = (uint32_t)__float2int_rn((dy + 1.f) * 31.5f);
            nv[m] = (uint32_t)n | (qx << 20) | (qy << 26);
            s0 += du * dx;
            s1 += du * dy;
            t0 += du1 * dx;
            t1 += du1 * dy;
          }
        }
      }
      asm volatile("" ::: "memory");
#pragma unroll
      for (int m = 0; m < M; ++m) ndv_lds[(p * M + m) * 256 + lt] = nv[m];
      uint32_t iq = invq[p];
      float a = e4m3_byte(iq, 0), b = e4m3_byte(iq, 1);
      float c = e4m3_byte(iq, 2), d = e4m3_byte(iq, 3);
      uint32_t w2 = pack_e4m3x4(s0 * a + s1 * c, s0 * b + s1 * d,
                                t0 * a + t1 * c, t0 * b + t1 * d);
      pw2[p] = w2;
      packed2[i] = w2;
    }
  }
  __threadfence();
  grid.sync();
  __threadfence();

#pragma unroll
  for (int p = 0; p < P; ++p) {
    int i = tid + p * T;
    if (i < N) {
      uint32_t pw = pw2[p];
      float gxi = e4m3_byte(pw, 0), gyi = e4m3_byte(pw, 1);
      float g1xi = e4m3_byte(pw, 2), g1yi = e4m3_byte(pw, 3);
      float a00 = 0.f, a01 = 0.f, a10 = 0.f, a11 = 0.f;
      float b00 = 0.f, b01 = 0.f, b10 = 0.f, b11 = 0.f;
      for (int w = 0; w < NWIN; ++w) {
        int lo = w * q;
#pragma unroll
        for (int m = 0; m < M; ++m) {
          uint32_t nvv = ndv_lds[(p * M + m) * 256 + lt];
          int n = (int)(nvv & 0xFFFFFu);
          if ((unsigned)(n - lo) < (unsigned)q) {
            uint32_t qw = packed2[n];
            float dx = (float)((nvv >> 20) & 63u) * (1.f / 31.5f) - 1.f;
            float dy = (float)((nvv >> 26) & 63u) * (1.f / 31.5f) - 1.f;
            float ux = e4m3_byte(qw, 0) - gxi;
            float uy = e4m3_byte(qw, 1) - gyi;
            a00 += ux * dx; a01 += ux * dy; a10 += uy * dx; a11 += uy * dy;
            float vx = e4m3_byte(qw, 2) - g1xi;
            float vy = e4m3_byte(qw, 3) - g1yi;
            b00 += vx * dx; b01 += vx * dy; b10 += vy * dx; b11 += vy * dy;
          }
        }
      }
      uint32_t iq = invq[p];
      float ia = e4m3_byte(iq, 0), ib = e4m3_byte(iq, 1);
      float ic = e4m3_byte(iq, 2), id = e4m3_byte(iq, 3);
      float uxx = a00 * ia + a01 * ic;
      float uyy = a10 * ib + a11 * id;
      float uxx1 = b00 * ia + b01 * ic;
      float uyy1 = b10 * ib + b11 * id;
      float f = (float)f0r[p] - 1e-4f * (uxx + uyy + uxx1 + uyy1);
      part += 4.f * f * f;
    }
  }
  block_reduce_atomic(part, out, threadIdx.x);
}

// ======================= fallback (non-cooperative) path =====================
__global__ __launch_bounds__(256) void pack_kernel(
    const float2* __restrict__ x,
    const float* __restrict__ ut,
    const float* __restrict__ ut1,
    const float* __restrict__ up,
    const float* __restrict__ usol,
    const float4* __restrict__ inv,
    uint32_t* __restrict__ packed1,
    uint2* __restrict__ selfdat,
    float* __restrict__ out,
    int N) {
  int i = blockIdx.x * blockDim.x + threadIdx.x;
  float part = 0.f;
  if (i < N) {
    float2 xi = x[i];
    uint32_t bx = (uint32_t)__float2int_rn(xi.x * 255.f);
    uint32_t by = (uint32_t)__float2int_rn(xi.y * 255.f);
    float u = __builtin_nontemporal_load(&ut[i]);
    float u1 = __builtin_nontemporal_load(&ut1[i]);
    __hip_fp8_e4m3 eu(u), eu1(u1);
    packed1[i] = bx | (by << 8) | ((uint32_t)eu.__x << 16) | ((uint32_t)eu1.__x << 24);
    float f0v = u1 - u - 0.01f * (u - u * u * u + u1 - u1 * u1 * u1);
    h16 f0h = (h16)f0v;
    unsigned short f0b = *(unsigned short*)&f0h;
    float4 iv = inv[i];
    uint2 sd;
    sd.x = pack_e4m3x4(iv.x, iv.y, iv.z, iv.w);
    sd.y = (uint32_t)f0b;
    selfdat[i] = sd;
    float du = __builtin_nontemporal_load(&up[i]) -
               __builtin_nontemporal_load(&usol[i]);
    part = du * du;
  }
  block_reduce_atomic(part, out, threadIdx.x);
}

__global__ __launch_bounds__(256) void grad1_kernel(
    const uint32_t* __restrict__ packed1,
    const int* __restrict__ nidx,
    const uint2* __restrict__ selfdat,
    uint32_t* __restrict__ packed2,
    uint32_t* __restrict__ nd,
    int N) {
  int i = blockIdx.x * blockDim.x + threadIdx.x;
  if (i >= N) return;
  uint32_t pw = packed1[i];
  float xi = (float)(pw & 0xffu) * (1.f / 255.f);
  float yi = (float)((pw >> 8) & 0xffu) * (1.f / 255.f);
  float ui = e4m3_byte(pw, 2);
  float u1i = e4m3_byte(pw, 3);
  int idx[M];
#pragma unroll
  for (int m = 0; m < M; ++m)
    idx[m] = __builtin_nontemporal_load(&nidx[(size_t)i * M + m]);
  float s0 = 0.f, s1 = 0.f, t0 = 0.f, t1 = 0.f;
  uint32_t ndv[M];
  int q = (N + NWIN - 1) / NWIN;
  for (int w = 0; w < NWIN; ++w) {
    int lo = w * q;
#pragma unroll
    for (int m = 0; m < M; ++m) {
      int n = idx[m];
      if ((unsigned)(n - lo) < (unsigned)q) {
        uint32_t qw = packed1[n];
        float dx = (float)(qw & 0xffu) * (1.f / 255.f) - xi;
        float dy = (float)((qw >> 8) & 0xffu) * (1.f / 255.f) - yi;
        float du = e4m3_byte(qw, 2) - ui;
        float du1 = e4m3_byte(qw, 3) - u1i;
        uint32_t qx = (uint32_t)__float2int_rn((dx + 1.f) * 31.5f);
        uint32_t qy = (uint32_t)__float2int_rn((dy + 1.f) * 31.5f);
        ndv[m] = (uint32_t)n | (qx << 20) | (qy << 26);
        s0 += du * dx;
        s1 += du * dy;
        t0 += du1 * dx;
        t1 += du1 * dy;
      }
    }
  }
  if (nd) {
#pragma unroll
    for (int m = 0; m < M; ++m)
      __builtin_nontemporal_store(ndv[m], &nd[(size_t)m * N + i]);
  }
  uint32_t iq = selfdat[i].x;
  float a = e4m3_byte(iq, 0), b = e4m3_byte(iq, 1);
  float c = e4m3_byte(iq, 2), d = e4m3_byte(iq, 3);
  packed2[i] = pack_e4m3x4(s0 * a + s1 * c, s0 * b + s1 * d,
                           t0 * a + t1 * c, t0 * b + t1 * d);
}

__global__ __launch_bounds__(256) void loss_kernel(
    const uint32_t* __restrict__ packed2,
    const uint32_t* __restrict__ packed1,
    const int* __restrict__ nidx,
    const uint32_t* __restrict__ nd,
    const uint2* __restrict__ selfdat,
    float* __restrict__ out,
    int N) {
  int i = blockIdx.x * blockDim.x + threadIdx.x;
  float part = 0.f;
  if (i < N) {
    uint32_t pw = packed2[i];
    float gxi = e4m3_byte(pw, 0), gyi = e4m3_byte(pw, 1);
    float g1xi = e4m3_byte(pw, 2), g1yi = e4m3_byte(pw, 3);
    uint32_t ndv[M];
    float xi = 0.f, yi = 0.f;
    if (nd) {
#pragma unroll
      for (int m = 0; m < M; ++m)
        ndv[m] = __builtin_nontemporal_load(&nd[(size_t)m * N + i]);
    } else {
#pragma unroll
      for (int m = 0; m < M; ++m)
        ndv[m] = (uint32_t)__builtin_nontemporal_load(&nidx[(size_t)i * M + m]);
      uint32_t w0 = packed1[i];
      xi = (float)(w0 & 0xffu) * (1.f / 255.f);
      yi = (float)((w0 >> 8) & 0xffu) * (1.f / 255.f);
    }
    float a00 = 0.f, a01 = 0.f, a10 = 0.f, a11 = 0.f;
    float b00 = 0.f, b01 = 0.f, b10 = 0.f, b11 = 0.f;
    int q = (N + NWIN - 1) / NWIN;
    for (int w = 0; w < NWIN; ++w) {
      int lo = w * q;
#pragma unroll
      for (int m = 0; m < M; ++m) {
        int n = (int)(ndv[m] & 0xFFFFFu);
        if ((unsigned)(n - lo) < (unsigned)q) {
          uint32_t qw = packed2[n];
          float dx, dy;
          if (nd) {
            dx = (float)((ndv[m] >> 20) & 63u) * (1.f / 31.5f) - 1.f;
            dy = (float)((ndv[m] >> 26) & 63u) * (1.f / 31.5f) - 1.f;
          } else {
            uint32_t wq = packed1[n];
            dx = (float)(wq & 0xffu) * (1.f / 255.f) - xi;
            dy = (float)((wq >> 8) & 0xffu) * (1.f / 255.f) - yi;
          }
          float ux = e4m3_byte(qw, 0) - gxi;
          float uy = e4m3_byte(qw, 1) - gyi;
          a00 += ux * dx; a01 += ux * dy; a10 += uy * dx; a11 += uy * dy;
          float vx = e4m3_byte(qw, 2) - g1xi;
          float vy = e4m3_byte(qw, 3) - g1yi;
          b00 += vx * dx; b01 += vx * dy; b10 += vy * dx; b11 += vy * dy;
        }
      }
    }
    uint2 sd = selfdat[i];
    float ia = e4m3_byte(sd.x, 0), ib = e4m3_byte(sd.x, 1);
    float ic = e4m3_byte(sd.x, 2), id = e4m3_byte(sd.x, 3);
    float uxx = a00 * ia + a01 * ic;
    float uyy = a10 * ib + a11 * id;
    float uxx1 = b00 * ia + b01 * ic;
    float uyy1 = b10 * ib + b11 * id;
    unsigned short f0b = (unsigned short)(sd.y & 0xffffu);
    float f = (float)*(h16*)&f0b - 1e-4f * (uxx + uyy + uxx1 + uyy1);
    part = 4.f * f * f;
  }
  block_reduce_atomic(part, out, threadIdx.x);
}

extern "C" void kernel_launch(void* const* d_in, const int* in_sizes, int n_in,
                              void* d_out, int out_size, void* d_ws, size_t ws_size,
                              hipStream_t stream) {
  const int N = in_sizes[0];  // up is (N,1)
  const float* up = (const float*)d_in[0];
  const float* usol = (const float*)d_in[1];
  const float* ut = (const float*)d_in[2];
  const float2* x = (const float2*)d_in[3];
  const float* ut1 = (const float*)d_in[4];
  const int* nidx = (const int*)d_in[5];
  const float4* inv = (const float4*)d_in[6];

  float* out = (float*)d_out;
  hipMemsetAsync(d_out, 0, out_size * sizeof(float), stream);

  int dev = 0, numCU = 0;
  bool devok =
      (hipGetDevice(&dev) == hipSuccess) &&
      (hipDeviceGetAttribute(&numCU, hipDeviceAttributeMultiprocessorCount,
                             dev) == hipSuccess) &&
      numCU > 0;

  // ---- primary: bucketed-sweep cooperative kernel ----
  if (devok && N <= (1 << 20)) {
    int nblk = (N + BPTS - 1) / BPTS;
    int nb = (N + GRAN - 1) / GRAN;
    size_t szPad = (size_t)((nb + 1) / 2) * WS2 * 4;  // padded packed arrays
    size_t szItems = (size_t)nblk * BPTS * M * 4;
    size_t need = 2 * szPad + szItems;
    if (nblk <= 256 && nb <= 256 && ws_size >= need) {
      uint32_t* p1 = (uint32_t*)d_ws;
      uint32_t* p2 = (uint32_t*)((char*)d_ws + szPad);
      uint32_t* items = (uint32_t*)((char*)d_ws + 2 * szPad);
      int maxB = 0;
      if (hipOccupancyMaxActiveBlocksPerMultiprocessor(&maxB, fused_bucket,
                                                       BLK, 0) == hipSuccess &&
          maxB > 0 && nblk <= maxB * numCU) {
        void* args[] = {(void*)&x,    (void*)&ut, (void*)&ut1,
                        (void*)&up,   (void*)&usol, (void*)&inv,
                        (void*)&nidx, (void*)&p1,   (void*)&p2,
                        (void*)&items, (void*)&out, (void*)&N};
        hipError_t err = hipLaunchCooperativeKernel(
            (const void*)fused_bucket, dim3(nblk), dim3(BLK), args, 0, stream);
        if (err == hipSuccess) return;
      }
    }
  }

  // ---- secondary: previous fused kernel ----
  size_t szP1 = (size_t)N * 4;
  size_t szP2 = (size_t)N * 4;
  size_t szSD = (size_t)N * 8;
  size_t szND = (size_t)N * M * 4;
  char* base = (char*)d_ws;
  uint32_t* packed1 = (uint32_t*)base;
  uint32_t* packed2 = (uint32_t*)(base + szP1);
  uint2* selfdat = (uint2*)(base + szP1 + szP2);
  uint32_t* nd = nullptr;
  if (ws_size >= szP1 + szP2 + szSD + szND) {
    nd = (uint32_t*)(base + szP1 + szP2 + szSD);
  }
  const int block = 256;

  if (devok && ws_size >= szP1 + szP2) {
    void* args[] = {(void*)&x,    (void*)&ut,      (void*)&ut1,
                    (void*)&up,   (void*)&usol,    (void*)&inv,
                    (void*)&nidx, (void*)&packed1, (void*)&packed2,
                    (void*)&out,  (void*)&N};
    {
      int need2 = (N + block * 2 - 1) / (block * 2);
      if (need2 < 1) need2 = 1;
      int maxB = 0;
      if (hipOccupancyMaxActiveBlocksPerMultiprocessor(&maxB, fused_t<2, 8>,
                                                       block, 0) == hipSuccess &&
          maxB > 0 && need2 <= maxB * numCU) {
        hipError_t err = hipLaunchCooperativeKernel(
            (const void*)(fused_t<2, 8>), dim3(need2), dim3(block), args, 0,
            stream);
        if (err == hipSuccess) return;
      }
    }
    {
      int need4 = (N + block * 4 - 1) / (block * 4);
      if (need4 < 1) need4 = 1;
      int maxB = 0;
      if (hipOccupancyMaxActiveBlocksPerMultiprocessor(&maxB, fused_t<4, 4>,
                                                       block, 0) == hipSuccess &&
          maxB > 0 && need4 <= maxB * numCU) {
        hipError_t err = hipLaunchCooperativeKernel(
            (const void*)(fused_t<4, 4>), dim3(need4), dim3(block), args, 0,
            stream);
        if (err == hipSuccess) return;
      }
    }
  }

  // ---- fallback: 3-kernel path ----
  const int grid = (N + block - 1) / block;
  pack_kernel<<<grid, block, 0, stream>>>(x, ut, ut1, up, usol, inv,
                                          packed1, selfdat, out, N);
  grad1_kernel<<<grid, block, 0, stream>>>(packed1, nidx, selfdat, packed2, nd, N);
  loss_kernel<<<grid, block, 0, stream>>>(packed2, packed1, nidx, nd, selfdat,
                                          out, N);
}

// Round 4
// 284.035 us; speedup vs baseline: 1.0012x; 1.0012x over previous
//
#include <hip/hip_runtime.h>
#include <hip/hip_fp16.h>
#include <hip/hip_fp8.h>

#define M 9
#define NWIN 2
typedef _Float16 h16;

// R4: the timing harness runs kernel_launch under hipGraph capture;
// hipLaunchCooperativeKernel is NOT capturable, so every previous round
// silently timed the non-cooperative 3-kernel fallback (hence four
// structurally different "primary" kernels all scoring 283.6-284.9 us, and
// bit-identical absmax across rounds). The cooperative paths are deleted;
// this file optimizes the path that is actually timed, with numerics kept
// bit-identical to the verified fallback:
//   - __launch_bounds__(256,8) on gather kernels (VGPR<=64, 32 waves/CU)
//   - nidx read wave-coalesced via per-wave LDS transpose (9x 256B loads
//     per wave instead of 9 loads spanning 36 cache lines each)
//
//   packed1[i] (4B): x:u8 | y:u8 | ut:fp8 | ut1:fp8   -- 4 MB gather array
//   packed2[i] (4B): gx,gy,g1x,g1y fp8                -- 4 MB gather array
//   nd[m*N+i] (4B): n:20 | qx:6 | qy:6                -- fused idx+dx,dy

__device__ __forceinline__ uint32_t pack_e4m3x4(float a, float b, float c, float d) {
  __hip_fp8_e4m3 pa(a), pb(b), pc(c), pd(d);
  return (uint32_t)pa.__x | ((uint32_t)pb.__x << 8) |
         ((uint32_t)pc.__x << 16) | ((uint32_t)pd.__x << 24);
}
__device__ __forceinline__ float e4m3_byte(uint32_t w, int byte) {
  __hip_fp8_e4m3 t;
  t.__x = (__hip_fp8_storage_t)((w >> (8 * byte)) & 0xffu);
  return (float)t;
}

__device__ __forceinline__ void block_reduce_atomic(float part, float* out,
                                                    int tid) {
#pragma unroll
  for (int off = 32; off > 0; off >>= 1) part += __shfl_down(part, off, 64);
  __shared__ float sbuf[4];
  int lane = tid & 63;
  int wave = tid >> 6;
  if (lane == 0) sbuf[wave] = part;
  __syncthreads();
  if (tid == 0) atomicAdd(out, sbuf[0] + sbuf[1] + sbuf[2] + sbuf[3]);
}

// ---- kernel 1: pack granule, self tables, loss_u ---------------------------
__global__ __launch_bounds__(256, 8) void pack_kernel(
    const float2* __restrict__ x,
    const float* __restrict__ ut,
    const float* __restrict__ ut1,
    const float* __restrict__ up,
    const float* __restrict__ usol,
    const float4* __restrict__ inv,
    uint32_t* __restrict__ packed1,
    uint2* __restrict__ selfdat,
    float* __restrict__ out,
    int N) {
  int i = blockIdx.x * blockDim.x + threadIdx.x;
  float part = 0.f;
  if (i < N) {
    float2 xi = x[i];
    uint32_t bx = (uint32_t)__float2int_rn(xi.x * 255.f);  // x,y in [0,1)
    uint32_t by = (uint32_t)__float2int_rn(xi.y * 255.f);
    float u = __builtin_nontemporal_load(&ut[i]);
    float u1 = __builtin_nontemporal_load(&ut1[i]);
    __hip_fp8_e4m3 eu(u), eu1(u1);
    packed1[i] = bx | (by << 8) | ((uint32_t)eu.__x << 16) | ((uint32_t)eu1.__x << 24);
    float f0v = u1 - u - 0.01f * (u - u * u * u + u1 - u1 * u1 * u1);
    h16 f0h = (h16)f0v;
    unsigned short f0b = *(unsigned short*)&f0h;
    float4 iv = inv[i];
    uint2 sd;
    sd.x = pack_e4m3x4(iv.x, iv.y, iv.z, iv.w);
    sd.y = (uint32_t)f0b;
    selfdat[i] = sd;
    float du = __builtin_nontemporal_load(&up[i]) -
               __builtin_nontemporal_load(&usol[i]);
    part = du * du;
  }
  block_reduce_atomic(part, out, threadIdx.x);
}

// ---- kernel 2: first gradients; nidx wave-coalesced via LDS transpose ------
__global__ __launch_bounds__(256, 8) void grad1_kernel(
    const uint32_t* __restrict__ packed1,
    const int* __restrict__ nidx,
    const uint2* __restrict__ selfdat,
    uint32_t* __restrict__ packed2,
    uint32_t* __restrict__ nd,
    int N) {
  const int lt = (int)threadIdx.x;
  const int l = lt & 63;
  const int wv = lt >> 6;
  const int i = blockIdx.x * 256 + lt;

  // Per-wave transpose staging: wave wv owns xidx[wv*576 .. +576).
  // Write stride-1 (conflict-free); read stride-9 (2 lanes/bank, free).
  __shared__ uint32_t xidx[4 * 576];
  {
    int gbase = (blockIdx.x * 256 + wv * 64) * M;  // first dword of wave rows
    uint32_t* stg = &xidx[wv * 576];
#pragma unroll
    for (int m = 0; m < M; ++m) {
      int g = gbase + m * 64 + l;
      uint32_t v = 0u;
      if (g < N * M) v = (uint32_t)__builtin_nontemporal_load(&nidx[g]);
      stg[m * 64 + l] = v;
    }
  }
  asm volatile("" ::: "memory");  // keep ds_reads after staging ds_writes
  if (i >= N) return;

  uint32_t pw = packed1[i];
  float xi = (float)(pw & 0xffu) * (1.f / 255.f);
  float yi = (float)((pw >> 8) & 0xffu) * (1.f / 255.f);
  float ui = e4m3_byte(pw, 2);
  float u1i = e4m3_byte(pw, 3);
  int idx[M];
#pragma unroll
  for (int m = 0; m < M; ++m) idx[m] = (int)xidx[wv * 576 + l * M + m];
  float s0 = 0.f, s1 = 0.f, t0 = 0.f, t1 = 0.f;
  uint32_t ndv[M];
  int q = (N + NWIN - 1) / NWIN;
  for (int w = 0; w < NWIN; ++w) {
    int lo = w * q;
#pragma unroll
    for (int m = 0; m < M; ++m) {
      int n = idx[m];
      if ((unsigned)(n - lo) < (unsigned)q) {
        uint32_t qw = packed1[n];  // windowed gather: 2MB working set
        float dx = (float)(qw & 0xffu) * (1.f / 255.f) - xi;
        float dy = (float)((qw >> 8) & 0xffu) * (1.f / 255.f) - yi;
        float du = e4m3_byte(qw, 2) - ui;
        float du1 = e4m3_byte(qw, 3) - u1i;
        uint32_t qx = (uint32_t)__float2int_rn((dx + 1.f) * 31.5f);
        uint32_t qy = (uint32_t)__float2int_rn((dy + 1.f) * 31.5f);
        ndv[m] = (uint32_t)n | (qx << 20) | (qy << 26);
        s0 += du * dx;
        s1 += du * dy;
        t0 += du1 * dx;
        t1 += du1 * dy;
      }
    }
  }
  if (nd) {
#pragma unroll
    for (int m = 0; m < M; ++m)
      __builtin_nontemporal_store(ndv[m], &nd[(size_t)m * N + i]);
  }
  uint32_t iq = selfdat[i].x;
  float a = e4m3_byte(iq, 0), b = e4m3_byte(iq, 1);
  float c = e4m3_byte(iq, 2), d = e4m3_byte(iq, 3);
  packed2[i] = pack_e4m3x4(s0 * a + s1 * c, s0 * b + s1 * d,
                           t0 * a + t1 * c, t0 * b + t1 * d);
}

// ---- kernel 3: second-gradient diagonals + f + loss_f ----------------------
__global__ __launch_bounds__(256, 8) void loss_kernel(
    const uint32_t* __restrict__ packed2,
    const uint32_t* __restrict__ packed1,
    const int* __restrict__ nidx,
    const uint32_t* __restrict__ nd,
    const uint2* __restrict__ selfdat,
    float* __restrict__ out,
    int N) {
  const int lt = (int)threadIdx.x;
  const int l = lt & 63;
  const int wv = lt >> 6;
  const int i = blockIdx.x * 256 + lt;

  __shared__ uint32_t xidx[4 * 576];
  if (!nd) {  // only the no-nd branch needs raw nidx; stage it coalesced
    int gbase = (blockIdx.x * 256 + wv * 64) * M;
    uint32_t* stg = &xidx[wv * 576];
#pragma unroll
    for (int m = 0; m < M; ++m) {
      int g = gbase + m * 64 + l;
      uint32_t v = 0u;
      if (g < N * M) v = (uint32_t)__builtin_nontemporal_load(&nidx[g]);
      stg[m * 64 + l] = v;
    }
    asm volatile("" ::: "memory");
  }

  float part = 0.f;
  if (i < N) {
    uint32_t pw = packed2[i];
    float gxi = e4m3_byte(pw, 0), gyi = e4m3_byte(pw, 1);
    float g1xi = e4m3_byte(pw, 2), g1yi = e4m3_byte(pw, 3);
    uint32_t ndv[M];
    float xi = 0.f, yi = 0.f;
    if (nd) {
#pragma unroll
      for (int m = 0; m < M; ++m)
        ndv[m] = __builtin_nontemporal_load(&nd[(size_t)m * N + i]);
    } else {
#pragma unroll
      for (int m = 0; m < M; ++m) ndv[m] = xidx[wv * 576 + l * M + m];
      uint32_t w0 = packed1[i];
      xi = (float)(w0 & 0xffu) * (1.f / 255.f);
      yi = (float)((w0 >> 8) & 0xffu) * (1.f / 255.f);
    }
    float a00 = 0.f, a01 = 0.f, a10 = 0.f, a11 = 0.f;
    float b00 = 0.f, b01 = 0.f, b10 = 0.f, b11 = 0.f;
    int q = (N + NWIN - 1) / NWIN;
    for (int w = 0; w < NWIN; ++w) {
      int lo = w * q;
#pragma unroll
      for (int m = 0; m < M; ++m) {
        int n = (int)(ndv[m] & 0xFFFFFu);
        if ((unsigned)(n - lo) < (unsigned)q) {
          uint32_t qw = packed2[n];  // windowed gather: 2MB working set
          float dx, dy;
          if (nd) {
            dx = (float)((ndv[m] >> 20) & 63u) * (1.f / 31.5f) - 1.f;
            dy = (float)((ndv[m] >> 26) & 63u) * (1.f / 31.5f) - 1.f;
          } else {
            uint32_t wq = packed1[n];
            dx = (float)(wq & 0xffu) * (1.f / 255.f) - xi;
            dy = (float)((wq >> 8) & 0xffu) * (1.f / 255.f) - yi;
          }
          float ux = e4m3_byte(qw, 0) - gxi;
          float uy = e4m3_byte(qw, 1) - gyi;
          a00 += ux * dx; a01 += ux * dy; a10 += uy * dx; a11 += uy * dy;
          float vx = e4m3_byte(qw, 2) - g1xi;
          float vy = e4m3_byte(qw, 3) - g1yi;
          b00 += vx * dx; b01 += vx * dy; b10 += vy * dx; b11 += vy * dy;
        }
      }
    }
    uint2 sd = selfdat[i];
    float ia = e4m3_byte(sd.x, 0), ib = e4m3_byte(sd.x, 1);
    float ic = e4m3_byte(sd.x, 2), id = e4m3_byte(sd.x, 3);
    float uxx = a00 * ia + a01 * ic;
    float uyy = a10 * ib + a11 * id;
    float uxx1 = b00 * ia + b01 * ic;
    float uyy1 = b10 * ib + b11 * id;
    unsigned short f0b = (unsigned short)(sd.y & 0xffffu);
    float f = (float)*(h16*)&f0b - 1e-4f * (uxx + uyy + uxx1 + uyy1);
    part = 4.f * f * f;
  }
  block_reduce_atomic(part, out, threadIdx.x);
}

extern "C" void kernel_launch(void* const* d_in, const int* in_sizes, int n_in,
                              void* d_out, int out_size, void* d_ws, size_t ws_size,
                              hipStream_t stream) {
  const int N = in_sizes[0];  // up is (N,1)
  const float* up = (const float*)d_in[0];
  const float* usol = (const float*)d_in[1];
  const float* ut = (const float*)d_in[2];
  const float2* x = (const float2*)d_in[3];
  const float* ut1 = (const float*)d_in[4];
  const int* nidx = (const int*)d_in[5];
  const float4* inv = (const float4*)d_in[6];

  size_t szP1 = (size_t)N * 4;
  size_t szP2 = (size_t)N * 4;
  size_t szSD = (size_t)N * 8;
  size_t szND = (size_t)N * M * 4;

  char* base = (char*)d_ws;
  uint32_t* packed1 = (uint32_t*)base;
  uint32_t* packed2 = (uint32_t*)(base + szP1);
  uint2* selfdat = (uint2*)(base + szP1 + szP2);
  uint32_t* nd = nullptr;
  if (ws_size >= szP1 + szP2 + szSD + szND) {
    nd = (uint32_t*)(base + szP1 + szP2 + szSD);
  }
  float* out = (float*)d_out;

  hipMemsetAsync(d_out, 0, out_size * sizeof(float), stream);

  const int block = 256;
  const int grid = (N + block - 1) / block;
  pack_kernel<<<grid, block, 0, stream>>>(x, ut, ut1, up, usol, inv,
                                          packed1, selfdat, out, N);
  grad1_kernel<<<grid, block, 0, stream>>>(packed1, nidx, selfdat, packed2, nd, N);
  loss_kernel<<<grid, block, 0, stream>>>(packed2, packed1, nidx, nd, selfdat,
                                          out, N);
}